// Round 1
// baseline (1346.718 us; speedup 1.0000x reference)
//
#include <hip/hip_runtime.h>
#include <hip/hip_bf16.h>

#define NUM_NODES 50000
#define DIM 64
#define NUM_EDGES 800000
#define EPS 1e-12f

// ---------------- L2 normalize: one 64-lane wave per row ----------------
__global__ void l2norm_kernel(const float* __restrict__ in, float* __restrict__ out) {
    int row = blockIdx.x * (blockDim.x >> 6) + (threadIdx.x >> 6);
    int lane = threadIdx.x & 63;
    if (row >= NUM_NODES) return;
    float v = in[(long)row * DIM + lane];
    float s = v * v;
    // wave64 butterfly reduce
    #pragma unroll
    for (int off = 32; off > 0; off >>= 1)
        s += __shfl_xor(s, off, 64);
    float n = sqrtf(s);
    float inv = 1.0f / fmaxf(n, EPS);
    out[(long)row * DIM + lane] = v * inv;
}

// ---------------- degree: atomic count of dst ----------------
__global__ void degree_kernel(const int* __restrict__ dst, float* __restrict__ deg) {
    int e = blockIdx.x * blockDim.x + threadIdx.x;
    if (e >= NUM_EDGES) return;
    atomicAdd(&deg[dst[e]], 1.0f);
}

// ---------------- dinv = deg>0 ? rsqrt(deg) : 0 (in place) ----------------
__global__ void dinv_kernel(float* __restrict__ deg) {
    int i = blockIdx.x * blockDim.x + threadIdx.x;
    if (i >= NUM_NODES) return;
    float d = deg[i];
    deg[i] = (d > 0.0f) ? rsqrtf(d) : 0.0f;
}

// ---------------- LGConv scatter: one lane per (edge, dim) ----------------
__global__ void conv_kernel(const float* __restrict__ xin,
                            const float* __restrict__ dinv,
                            const int* __restrict__ src,
                            const int* __restrict__ dst,
                            float* __restrict__ out) {
    long i = (long)blockIdx.x * blockDim.x + threadIdx.x;
    long e = i >> 6;
    if (e >= NUM_EDGES) return;
    int d = (int)(i & 63);
    int s = src[e];
    int t = dst[e];
    float norm = dinv[s] * dinv[t];
    float v = norm * xin[(long)s * DIM + d];
    atomicAdd(&out[(long)t * DIM + d], v);
}

// ---------------- final: l2-normalize + weighted accumulate ----------------
__global__ void finalize_kernel(const float* __restrict__ in,
                                const float* __restrict__ alpha,
                                int which, float* __restrict__ out) {
    int row = blockIdx.x * (blockDim.x >> 6) + (threadIdx.x >> 6);
    int lane = threadIdx.x & 63;
    if (row >= NUM_NODES) return;

    // softmax(alpha) -> clip 1e-4 -> renormalize, pick w[which]
    float a0 = alpha[0], a1 = alpha[1], a2 = alpha[2];
    float m = fmaxf(a0, fmaxf(a1, a2));
    float e0 = expf(a0 - m), e1 = expf(a1 - m), e2 = expf(a2 - m);
    float es = e0 + e1 + e2;
    float w0 = fmaxf(e0 / es, 1e-4f);
    float w1 = fmaxf(e1 / es, 1e-4f);
    float w2 = fmaxf(e2 / es, 1e-4f);
    float ws = w0 + w1 + w2;
    float w = ((which == 0) ? w0 : (which == 1) ? w1 : w2) / ws;

    float v = in[(long)row * DIM + lane];
    float s = v * v;
    #pragma unroll
    for (int off = 32; off > 0; off >>= 1)
        s += __shfl_xor(s, off, 64);
    float n = sqrtf(s);
    float inv = 1.0f / fmaxf(n, EPS);
    float val = w * v * inv;

    long idx = (long)row * DIM + lane;
    if (which == 0)
        out[idx] = val;          // first set overwrites (d_out is poisoned)
    else
        out[idx] += val;
}

extern "C" void kernel_launch(void* const* d_in, const int* in_sizes, int n_in,
                              void* d_out, int out_size, void* d_ws, size_t ws_size,
                              hipStream_t stream) {
    const float* x     = (const float*)d_in[0];
    const float* alpha = (const float*)d_in[1];
    const int* ei[3]   = { (const int*)d_in[2], (const int*)d_in[3], (const int*)d_in[4] };

    float* out = (float*)d_out;

    // workspace layout
    float* xn   = (float*)d_ws;                       // 50000*64
    float* bufA = xn   + (long)NUM_NODES * DIM;       // 50000*64
    float* bufB = bufA + (long)NUM_NODES * DIM;       // 50000*64
    float* dinv = bufB + (long)NUM_NODES * DIM;       // 50000

    const size_t tbl_bytes = (size_t)NUM_NODES * DIM * sizeof(float);
    const size_t deg_bytes = (size_t)NUM_NODES * sizeof(float);

    // 1. normalize input
    {
        dim3 blk(256);
        dim3 grd((NUM_NODES * 64 + 255) / 256);
        l2norm_kernel<<<grd, blk, 0, stream>>>(x, xn);
    }

    for (int g = 0; g < 3; ++g) {
        const int* src = ei[g];                 // row 0
        const int* dst = ei[g] + NUM_EDGES;     // row 1

        // degree -> dinv
        hipMemsetAsync(dinv, 0, deg_bytes, stream);
        degree_kernel<<<(NUM_EDGES + 255) / 256, 256, 0, stream>>>(dst, dinv);
        dinv_kernel<<<(NUM_NODES + 255) / 256, 256, 0, stream>>>(dinv);

        // layer 1: xn -> bufA
        hipMemsetAsync(bufA, 0, tbl_bytes, stream);
        {
            long total = (long)NUM_EDGES * 64;
            conv_kernel<<<(unsigned)((total + 255) / 256), 256, 0, stream>>>(xn, dinv, src, dst, bufA);
        }
        // layer 2: bufA -> bufB
        hipMemsetAsync(bufB, 0, tbl_bytes, stream);
        {
            long total = (long)NUM_EDGES * 64;
            conv_kernel<<<(unsigned)((total + 255) / 256), 256, 0, stream>>>(bufA, dinv, src, dst, bufB);
        }

        // finalize: normalize bufB, weight, accumulate into out
        {
            dim3 blk(256);
            dim3 grd((NUM_NODES * 64 + 255) / 256);
            finalize_kernel<<<grd, blk, 0, stream>>>(bufB, alpha, g, out);
        }
    }
}

// Round 2
// 662.952 us; speedup vs baseline: 2.0314x; 2.0314x over previous
//
#include <hip/hip_runtime.h>
#include <hip/hip_bf16.h>

#define NUM_NODES 50000
#define DIM 64
#define NUM_EDGES 800000
#define EPS 1e-12f
#define SCAN_BLK 256
#define NUM_CHUNKS ((NUM_NODES + SCAN_BLK - 1) / SCAN_BLK)   // 196

// ---------------- L2 normalize input: one 64-lane wave per row ----------------
__global__ void l2norm_kernel(const float* __restrict__ in, float* __restrict__ out) {
    int row = blockIdx.x * (blockDim.x >> 6) + (threadIdx.x >> 6);
    int lane = threadIdx.x & 63;
    if (row >= NUM_NODES) return;
    float v = in[(long)row * DIM + lane];
    float s = v * v;
    #pragma unroll
    for (int off = 32; off > 0; off >>= 1)
        s += __shfl_xor(s, off, 64);
    float inv = 1.0f / fmaxf(sqrtf(s), EPS);
    out[(long)row * DIM + lane] = v * inv;
}

// ---------------- histogram of dst ----------------
__global__ void hist_kernel(const int* __restrict__ dst, int* __restrict__ cnt) {
    int e = blockIdx.x * blockDim.x + threadIdx.x;
    if (e >= NUM_EDGES) return;
    atomicAdd(&cnt[dst[e]], 1);
}

// ---------------- scan stage 1: per-chunk sums ----------------
__global__ void scan_partials_kernel(const int* __restrict__ cnt, int* __restrict__ partial) {
    int t = threadIdx.x;
    int i = blockIdx.x * SCAN_BLK + t;
    int v = (i < NUM_NODES) ? cnt[i] : 0;
    // wave reduce then LDS across 4 waves
    #pragma unroll
    for (int off = 32; off > 0; off >>= 1)
        v += __shfl_xor(v, off, 64);
    __shared__ int sw[4];
    if ((t & 63) == 0) sw[t >> 6] = v;
    __syncthreads();
    if (t == 0) partial[blockIdx.x] = sw[0] + sw[1] + sw[2] + sw[3];
}

// ---------------- scan stage 2: exclusive-scan the 196 partials (1 block) ----------------
__global__ void scan_single_kernel(const int* __restrict__ partial, int* __restrict__ pscan) {
    int t = threadIdx.x;
    int v = (t < NUM_CHUNKS) ? partial[t] : 0;
    __shared__ int sd[SCAN_BLK];
    sd[t] = v;
    __syncthreads();
    #pragma unroll
    for (int off = 1; off < SCAN_BLK; off <<= 1) {
        int add = (t >= off) ? sd[t - off] : 0;
        __syncthreads();
        sd[t] += add;
        __syncthreads();
    }
    if (t < NUM_CHUNKS) pscan[t] = sd[t] - v;   // exclusive
}

// ---------------- scan stage 3: per-chunk exclusive scan + offset ----------------
__global__ void scan_apply_kernel(const int* __restrict__ cnt, const int* __restrict__ pscan,
                                  int* __restrict__ row_start) {
    int t = threadIdx.x;
    int i = blockIdx.x * SCAN_BLK + t;
    int v = (i < NUM_NODES) ? cnt[i] : 0;
    __shared__ int sd[SCAN_BLK];
    sd[t] = v;
    __syncthreads();
    #pragma unroll
    for (int off = 1; off < SCAN_BLK; off <<= 1) {
        int add = (t >= off) ? sd[t - off] : 0;
        __syncthreads();
        sd[t] += add;
        __syncthreads();
    }
    if (i < NUM_NODES) row_start[i] = pscan[blockIdx.x] + sd[t] - v;
    if (i == 0) row_start[NUM_NODES] = NUM_EDGES;
}

// ---------------- prep: dinv from degree; cursor = row_start copy ----------------
__global__ void prep_kernel(const int* __restrict__ row_start, float* __restrict__ dinv,
                            int* __restrict__ cursor) {
    int i = blockIdx.x * blockDim.x + threadIdx.x;
    if (i >= NUM_NODES) return;
    int rs = row_start[i];
    int deg = row_start[i + 1] - rs;
    dinv[i] = (deg > 0) ? rsqrtf((float)deg) : 0.0f;
    cursor[i] = rs;
}

// ---------------- scatter edges into CSR with premultiplied norm ----------------
__global__ void scatter_kernel(const int* __restrict__ src, const int* __restrict__ dst,
                               const float* __restrict__ dinv, int* __restrict__ cursor,
                               int2* __restrict__ esort) {
    int e = blockIdx.x * blockDim.x + threadIdx.x;
    if (e >= NUM_EDGES) return;
    int s = src[e];
    int t = dst[e];
    float norm = dinv[s] * dinv[t];
    int pos = atomicAdd(&cursor[t], 1);
    int2 p;
    p.x = s;
    p.y = __float_as_int(norm);
    esort[pos] = p;
}

// ---------------- gather conv: one wave per output row, no atomics ----------------
__global__ void conv_gather_kernel(const float* __restrict__ xin,
                                   const int2* __restrict__ esort,
                                   const int* __restrict__ row_start,
                                   float* __restrict__ out) {
    int row = blockIdx.x * (blockDim.x >> 6) + (threadIdx.x >> 6);
    int lane = threadIdx.x & 63;
    if (row >= NUM_NODES) return;
    int start = row_start[row];
    int end = row_start[row + 1];
    float acc = 0.0f;
    int i = start;
    for (; i + 1 < end; i += 2) {
        int2 p0 = esort[i];
        int2 p1 = esort[i + 1];
        float v0 = xin[(long)p0.x * DIM + lane];
        float v1 = xin[(long)p1.x * DIM + lane];
        acc += __int_as_float(p0.y) * v0;
        acc += __int_as_float(p1.y) * v1;
    }
    if (i < end) {
        int2 p = esort[i];
        acc += __int_as_float(p.y) * xin[(long)p.x * DIM + lane];
    }
    out[(long)row * DIM + lane] = acc;
}

// ---------------- gather conv (layer 2) fused with l2norm + weighted accumulate ----------------
__global__ void conv2_finalize_kernel(const float* __restrict__ xin,
                                      const int2* __restrict__ esort,
                                      const int* __restrict__ row_start,
                                      const float* __restrict__ alpha,
                                      int which, float* __restrict__ out) {
    int row = blockIdx.x * (blockDim.x >> 6) + (threadIdx.x >> 6);
    int lane = threadIdx.x & 63;
    if (row >= NUM_NODES) return;
    int start = row_start[row];
    int end = row_start[row + 1];
    float acc = 0.0f;
    int i = start;
    for (; i + 1 < end; i += 2) {
        int2 p0 = esort[i];
        int2 p1 = esort[i + 1];
        float v0 = xin[(long)p0.x * DIM + lane];
        float v1 = xin[(long)p1.x * DIM + lane];
        acc += __int_as_float(p0.y) * v0;
        acc += __int_as_float(p1.y) * v1;
    }
    if (i < end) {
        int2 p = esort[i];
        acc += __int_as_float(p.y) * xin[(long)p.x * DIM + lane];
    }

    // row L2 norm (the wave holds the whole row)
    float s = acc * acc;
    #pragma unroll
    for (int off = 32; off > 0; off >>= 1)
        s += __shfl_xor(s, off, 64);
    float inv = 1.0f / fmaxf(sqrtf(s), EPS);

    // softmax(alpha) -> clip -> renormalize, pick w[which]
    float a0 = alpha[0], a1 = alpha[1], a2 = alpha[2];
    float m = fmaxf(a0, fmaxf(a1, a2));
    float e0 = expf(a0 - m), e1 = expf(a1 - m), e2 = expf(a2 - m);
    float es = e0 + e1 + e2;
    float w0 = fmaxf(e0 / es, 1e-4f);
    float w1 = fmaxf(e1 / es, 1e-4f);
    float w2 = fmaxf(e2 / es, 1e-4f);
    float ws = w0 + w1 + w2;
    float w = ((which == 0) ? w0 : (which == 1) ? w1 : w2) / ws;

    float val = w * acc * inv;
    long idx = (long)row * DIM + lane;
    if (which == 0)
        out[idx] = val;
    else
        out[idx] += val;
}

extern "C" void kernel_launch(void* const* d_in, const int* in_sizes, int n_in,
                              void* d_out, int out_size, void* d_ws, size_t ws_size,
                              hipStream_t stream) {
    const float* x     = (const float*)d_in[0];
    const float* alpha = (const float*)d_in[1];
    const int* ei[3]   = { (const int*)d_in[2], (const int*)d_in[3], (const int*)d_in[4] };
    float* out = (float*)d_out;

    // workspace layout (all 8B-aligned by construction)
    float* xn        = (float*)d_ws;                    // 3,200,000
    float* bufA      = xn + (long)NUM_NODES * DIM;      // 3,200,000
    float* dinv      = bufA + (long)NUM_NODES * DIM;    // 50,000
    int*   cnt       = (int*)(dinv + NUM_NODES);        // 50,000 (reused as cursor)
    int*   row_start = cnt + NUM_NODES;                 // 50,001 (padded to 50,008)
    int*   partial   = row_start + 50008;               // 256
    int*   pscan     = partial + 256;                   // 256
    int2*  esort     = (int2*)(pscan + 256);            // 800,000 int2

    const int wave_grid = (NUM_NODES * 64 + 255) / 256; // 1 wave per row, 4 waves/block
    const int edge_grid = (NUM_EDGES + 255) / 256;
    const int node_grid = (NUM_NODES + 255) / 256;

    // normalize input once
    l2norm_kernel<<<wave_grid, 256, 0, stream>>>(x, xn);

    for (int g = 0; g < 3; ++g) {
        const int* src = ei[g];
        const int* dst = ei[g] + NUM_EDGES;

        // ---- build CSR ----
        hipMemsetAsync(cnt, 0, NUM_NODES * sizeof(int), stream);
        hist_kernel<<<edge_grid, 256, 0, stream>>>(dst, cnt);
        scan_partials_kernel<<<NUM_CHUNKS, SCAN_BLK, 0, stream>>>(cnt, partial);
        scan_single_kernel<<<1, SCAN_BLK, 0, stream>>>(partial, pscan);
        scan_apply_kernel<<<NUM_CHUNKS, SCAN_BLK, 0, stream>>>(cnt, pscan, row_start);
        prep_kernel<<<node_grid, 256, 0, stream>>>(row_start, dinv, cnt /*cursor*/);
        scatter_kernel<<<edge_grid, 256, 0, stream>>>(src, dst, dinv, cnt /*cursor*/, esort);

        // ---- layer 1: xn -> bufA ----
        conv_gather_kernel<<<wave_grid, 256, 0, stream>>>(xn, esort, row_start, bufA);
        // ---- layer 2 + normalize + weighted accumulate: bufA -> out ----
        conv2_finalize_kernel<<<wave_grid, 256, 0, stream>>>(bufA, esort, row_start, alpha, g, out);
    }
}

// Round 3
// 485.677 us; speedup vs baseline: 2.7729x; 1.3650x over previous
//
#include <hip/hip_runtime.h>
#include <hip/hip_bf16.h>

#define NUM_NODES 50000
#define DIM 64
#define NUM_EDGES 800000
#define NUM_GRAPHS 3
#define TOT_NODES (NUM_NODES * NUM_GRAPHS)      // 150000
#define TOT_EDGES (NUM_EDGES * NUM_GRAPHS)      // 2400000
#define EPS 1e-12f
#define SCAN_BLK 256
#define NUM_CHUNKS ((TOT_NODES + SCAN_BLK - 1) / SCAN_BLK)   // 586

typedef unsigned short ushort_t;
typedef unsigned int uint_t;

__device__ __forceinline__ float bf2f(ushort_t u) {
    return __uint_as_float(((uint_t)u) << 16);
}
__device__ __forceinline__ ushort_t f2bf(float f) {
    uint_t x = __float_as_uint(f);
    uint_t r = (x + 0x7FFFu + ((x >> 16) & 1u)) >> 16;   // RNE
    return (ushort_t)r;
}

// ---------------- L2 normalize input -> bf16: one wave per row ----------------
__global__ void l2norm_kernel(const float* __restrict__ in, ushort_t* __restrict__ out) {
    int row = blockIdx.x * (blockDim.x >> 6) + (threadIdx.x >> 6);
    int lane = threadIdx.x & 63;
    if (row >= NUM_NODES) return;
    float v = in[(long)row * DIM + lane];
    float s = v * v;
    #pragma unroll
    for (int off = 32; off > 0; off >>= 1)
        s += __shfl_xor(s, off, 64);
    float inv = 1.0f / fmaxf(sqrtf(s), EPS);
    out[(long)row * DIM + lane] = f2bf(v * inv);
}

// ---------------- histogram of dst for all 3 graphs ----------------
__global__ void hist3_kernel(const int* __restrict__ e0, const int* __restrict__ e1,
                             const int* __restrict__ e2, int* __restrict__ cnt) {
    int e = blockIdx.x * blockDim.x + threadIdx.x;
    int g = blockIdx.y;
    if (e >= NUM_EDGES) return;
    const int* dst = ((g == 0) ? e0 : (g == 1) ? e1 : e2) + NUM_EDGES;
    atomicAdd(&cnt[g * NUM_NODES + dst[e]], 1);
}

// ---------------- scan stage 1: per-chunk sums over 150000 counts ----------------
__global__ void scan_partials_kernel(const int* __restrict__ cnt, int* __restrict__ partial) {
    int t = threadIdx.x;
    int i = blockIdx.x * SCAN_BLK + t;
    int v = (i < TOT_NODES) ? cnt[i] : 0;
    #pragma unroll
    for (int off = 32; off > 0; off >>= 1)
        v += __shfl_xor(v, off, 64);
    __shared__ int sw[4];
    if ((t & 63) == 0) sw[t >> 6] = v;
    __syncthreads();
    if (t == 0) partial[blockIdx.x] = sw[0] + sw[1] + sw[2] + sw[3];
}

// ---------------- scan stage 2: exclusive-scan 586 partials (1 block of 1024) ----------------
__global__ void scan_single_kernel(const int* __restrict__ partial, int* __restrict__ pscan) {
    int t = threadIdx.x;
    int v = (t < NUM_CHUNKS) ? partial[t] : 0;
    __shared__ int sd[1024];
    sd[t] = v;
    __syncthreads();
    #pragma unroll
    for (int off = 1; off < 1024; off <<= 1) {
        int add = (t >= off) ? sd[t - off] : 0;
        __syncthreads();
        sd[t] += add;
        __syncthreads();
    }
    if (t < NUM_CHUNKS) pscan[t] = sd[t] - v;   // exclusive
}

// ---------------- scan stage 3: per-chunk exclusive scan + offset ----------------
__global__ void scan_apply_kernel(const int* __restrict__ cnt, const int* __restrict__ pscan,
                                  int* __restrict__ row_start) {
    int t = threadIdx.x;
    int i = blockIdx.x * SCAN_BLK + t;
    int v = (i < TOT_NODES) ? cnt[i] : 0;
    __shared__ int sd[SCAN_BLK];
    sd[t] = v;
    __syncthreads();
    #pragma unroll
    for (int off = 1; off < SCAN_BLK; off <<= 1) {
        int add = (t >= off) ? sd[t - off] : 0;
        __syncthreads();
        sd[t] += add;
        __syncthreads();
    }
    if (i < TOT_NODES) row_start[i] = pscan[blockIdx.x] + sd[t] - v;
    if (i == 0) row_start[TOT_NODES] = TOT_EDGES;
}

// ---------------- prep: dinv from degree; cursor = row_start copy ----------------
__global__ void prep_kernel(const int* __restrict__ row_start, float* __restrict__ dinv,
                            int* __restrict__ cursor) {
    int i = blockIdx.x * blockDim.x + threadIdx.x;
    if (i >= TOT_NODES) return;
    int rs = row_start[i];
    int deg = row_start[i + 1] - rs;
    dinv[i] = (deg > 0) ? rsqrtf((float)deg) : 0.0f;
    cursor[i] = rs;
}

// ---------------- scatter edges into concatenated CSR with premultiplied norm ----------------
__global__ void scatter3_kernel(const int* __restrict__ e0, const int* __restrict__ e1,
                                const int* __restrict__ e2,
                                const float* __restrict__ dinv, int* __restrict__ cursor,
                                int2* __restrict__ esort) {
    int e = blockIdx.x * blockDim.x + threadIdx.x;
    int g = blockIdx.y;
    if (e >= NUM_EDGES) return;
    const int* ei = (g == 0) ? e0 : (g == 1) ? e1 : e2;
    int s = ei[e];
    int t = ei[NUM_EDGES + e];
    float norm = dinv[g * NUM_NODES + s] * dinv[g * NUM_NODES + t];
    int pos = atomicAdd(&cursor[g * NUM_NODES + t], 1);
    int2 p;
    p.x = s;
    p.y = __float_as_int(norm);
    esort[pos] = p;
}

// ---------------- gather helper: one CSR row from a bf16 table ----------------
__device__ __forceinline__ float gather_row(const ushort_t* __restrict__ tbl,
                                            const int2* __restrict__ esort,
                                            int start, int end, int lane) {
    float acc = 0.0f;
    int i = start;
    for (; i + 4 <= end; i += 4) {
        int2 p0 = esort[i];
        int2 p1 = esort[i + 1];
        int2 p2 = esort[i + 2];
        int2 p3 = esort[i + 3];
        float v0 = bf2f(tbl[(long)p0.x * DIM + lane]);
        float v1 = bf2f(tbl[(long)p1.x * DIM + lane]);
        float v2 = bf2f(tbl[(long)p2.x * DIM + lane]);
        float v3 = bf2f(tbl[(long)p3.x * DIM + lane]);
        acc += __int_as_float(p0.y) * v0;
        acc += __int_as_float(p1.y) * v1;
        acc += __int_as_float(p2.y) * v2;
        acc += __int_as_float(p3.y) * v3;
    }
    for (; i < end; ++i) {
        int2 p = esort[i];
        acc += __int_as_float(p.y) * bf2f(tbl[(long)p.x * DIM + lane]);
    }
    return acc;
}

// ---------------- layer 1, all 3 graphs: xn -> bufA[g] ----------------
__global__ void conv1_all_kernel(const ushort_t* __restrict__ xn,
                                 const int2* __restrict__ esort,
                                 const int* __restrict__ row_start,
                                 ushort_t* __restrict__ bufA) {
    int row = blockIdx.x * (blockDim.x >> 6) + (threadIdx.x >> 6);
    int lane = threadIdx.x & 63;
    if (row >= NUM_NODES) return;
    #pragma unroll
    for (int g = 0; g < NUM_GRAPHS; ++g) {
        int k = g * NUM_NODES + row;
        int start = row_start[k];
        int end = row_start[k + 1];
        float acc = gather_row(xn, esort, start, end, lane);
        bufA[(long)k * DIM + lane] = f2bf(acc);
    }
}

// ---------------- layer 2 + l2norm + weighted blend, all 3 graphs -> out ----------------
__global__ void conv2_finalize_kernel(const ushort_t* __restrict__ bufA,
                                      const int2* __restrict__ esort,
                                      const int* __restrict__ row_start,
                                      const float* __restrict__ alpha,
                                      float* __restrict__ out) {
    int row = blockIdx.x * (blockDim.x >> 6) + (threadIdx.x >> 6);
    int lane = threadIdx.x & 63;
    if (row >= NUM_NODES) return;

    float res = 0.0f;

    // softmax(alpha) -> clip -> renormalize
    float a0 = alpha[0], a1 = alpha[1], a2 = alpha[2];
    float m = fmaxf(a0, fmaxf(a1, a2));
    float e0 = expf(a0 - m), e1 = expf(a1 - m), e2 = expf(a2 - m);
    float es = e0 + e1 + e2;
    float w0 = fmaxf(e0 / es, 1e-4f);
    float w1 = fmaxf(e1 / es, 1e-4f);
    float w2 = fmaxf(e2 / es, 1e-4f);
    float ws = w0 + w1 + w2;

    #pragma unroll
    for (int g = 0; g < NUM_GRAPHS; ++g) {
        int k = g * NUM_NODES + row;
        int start = row_start[k];
        int end = row_start[k + 1];
        const ushort_t* tbl = bufA + (long)g * NUM_NODES * DIM;
        float acc = gather_row(tbl, esort, start, end, lane);

        float s = acc * acc;
        #pragma unroll
        for (int off = 32; off > 0; off >>= 1)
            s += __shfl_xor(s, off, 64);
        float inv = 1.0f / fmaxf(sqrtf(s), EPS);
        float w = ((g == 0) ? w0 : (g == 1) ? w1 : w2) / ws;
        res += w * acc * inv;
    }

    out[(long)row * DIM + lane] = res;
}

extern "C" void kernel_launch(void* const* d_in, const int* in_sizes, int n_in,
                              void* d_out, int out_size, void* d_ws, size_t ws_size,
                              hipStream_t stream) {
    const float* x     = (const float*)d_in[0];
    const float* alpha = (const float*)d_in[1];
    const int* e0 = (const int*)d_in[2];
    const int* e1 = (const int*)d_in[3];
    const int* e2 = (const int*)d_in[4];
    float* out = (float*)d_out;

    // workspace layout
    ushort_t* xn   = (ushort_t*)d_ws;                          // 50000*64 bf16   (6.4 MB)
    ushort_t* bufA = xn + (long)NUM_NODES * DIM;               // 150000*64 bf16  (19.2 MB)
    int2* esort    = (int2*)(bufA + (long)TOT_NODES * DIM);    // 2400000 int2    (19.2 MB)
    float* dinv    = (float*)(esort + TOT_EDGES);              // 150000 f32
    int* cnt       = (int*)(dinv + TOT_NODES);                 // 150000 (reused as cursor)
    int* row_start = cnt + TOT_NODES;                          // 150001 (pad to 150008)
    int* partial   = row_start + 150008;                       // 1024
    int* pscan     = partial + 1024;                           // 1024

    const int wave_grid = (NUM_NODES * 64 + 255) / 256;        // 1 wave/row, 4 waves/block
    const int edge_blocks = (NUM_EDGES + 255) / 256;
    const int tnode_grid = (TOT_NODES + 255) / 256;

    // normalize input once (f32 -> bf16 table)
    l2norm_kernel<<<wave_grid, 256, 0, stream>>>(x, xn);

    // ---- build concatenated CSR for all 3 graphs ----
    hipMemsetAsync(cnt, 0, TOT_NODES * sizeof(int), stream);
    {
        dim3 grd(edge_blocks, NUM_GRAPHS);
        hist3_kernel<<<grd, 256, 0, stream>>>(e0, e1, e2, cnt);
    }
    scan_partials_kernel<<<NUM_CHUNKS, SCAN_BLK, 0, stream>>>(cnt, partial);
    scan_single_kernel<<<1, 1024, 0, stream>>>(partial, pscan);
    scan_apply_kernel<<<NUM_CHUNKS, SCAN_BLK, 0, stream>>>(cnt, pscan, row_start);
    prep_kernel<<<tnode_grid, 256, 0, stream>>>(row_start, dinv, cnt /*cursor*/);
    {
        dim3 grd(edge_blocks, NUM_GRAPHS);
        scatter3_kernel<<<grd, 256, 0, stream>>>(e0, e1, e2, dinv, cnt /*cursor*/, esort);
    }

    // ---- layer 1 (all graphs) ----
    conv1_all_kernel<<<wave_grid, 256, 0, stream>>>(xn, esort, row_start, bufA);
    // ---- layer 2 + normalize + blend (all graphs) ----
    conv2_finalize_kernel<<<wave_grid, 256, 0, stream>>>(bufA, esort, row_start, alpha, out);
}